// Round 20
// baseline (94.443 us; speedup 1.0000x reference)
//
#include <hip/hip_runtime.h>
#include <hip/hip_bf16.h>

typedef __bf16 bf16x4 __attribute__((ext_vector_type(4)));
typedef __bf16 bf16x8 __attribute__((ext_vector_type(8)));
typedef float  f32x4  __attribute__((ext_vector_type(4)));
typedef float  f32x16 __attribute__((ext_vector_type(16)));

constexpr int B = 2, S = 2048, D = 1024, H = 16, DK = 64;
constexpr int M = B * S;
constexpr int BH = B * H;

__device__ inline float fexp2(float x) {
#if __has_builtin(__builtin_amdgcn_exp2f)
  return __builtin_amdgcn_exp2f(x);
#else
  return exp2f(x);
#endif
}
__device__ inline float frcp(float x) {
#if __has_builtin(__builtin_amdgcn_rcpf)
  return __builtin_amdgcn_rcpf(x);
#else
  return 1.0f / x;
#endif
}
__device__ inline unsigned pk2(float lo, float hi) {
  union { __bf16 h[2]; unsigned u; } x;
  x.h[0] = (__bf16)lo; x.h[1] = (__bf16)hi;
  return x.u;
}

// ---------------- W [K][N] f32 -> WT [N][K] bf16, 3 in one launch ----------------
__global__ __launch_bounds__(256) void wtrans3(const float* __restrict__ w0,
                                               const float* __restrict__ w1,
                                               const float* __restrict__ w2,
                                               __bf16* __restrict__ t0,
                                               __bf16* __restrict__ t1,
                                               __bf16* __restrict__ t2) {
  int z = blockIdx.z;
  const float* W = z == 0 ? w0 : z == 1 ? w1 : w2;
  __bf16* WT = z == 0 ? t0 : z == 1 ? t1 : t2;
  __shared__ float t[32][33];
  int tx = threadIdx.x & 31, ty0 = threadIdx.x >> 5;
  int n0 = blockIdx.x * 32, k0 = blockIdx.y * 32;
#pragma unroll
  for (int i = 0; i < 4; ++i)
    t[ty0 + i * 8][tx] = W[(size_t)(k0 + ty0 + i * 8) * D + n0 + tx];
  __syncthreads();
#pragma unroll
  for (int i = 0; i < 4; ++i)
    WT[(size_t)(n0 + ty0 + i * 8) * D + k0 + tx] = (__bf16)t[tx][ty0 + i * 8];
}

// ---------------- merged projection GEMMs, f32-A fused conversion, BK=64 ----------------
constexpr int TM = 128, TN = 128, BK = 64;

__global__ __launch_bounds__(256, 3) void proj3(
    const float* __restrict__ X0, const float* __restrict__ X1,
    const float* __restrict__ X2, const __bf16* __restrict__ W0,
    const __bf16* __restrict__ W1, const __bf16* __restrict__ W2,
    const float* __restrict__ b0, const float* __restrict__ b1,
    const float* __restrict__ b2, __bf16* __restrict__ Qo,
    __bf16* __restrict__ Ko, __bf16* __restrict__ Vo) {
  __shared__ __align__(16) __bf16 As[TM * BK];      // 16 KB, single
  __shared__ __align__(16) __bf16 Bs[2][TN * BK];   // 2 x 16 KB
  int z = blockIdx.z;
  const float* A   = z == 0 ? X0 : z == 1 ? X1 : X2;
  const __bf16* BT = z == 0 ? W0 : z == 1 ? W1 : W2;
  const float* bias = z == 0 ? b0 : z == 1 ? b1 : b2;
  __bf16* out = z == 0 ? Qo : z == 1 ? Ko : Vo;
  int mode = (z == 2) ? 1 : 0;
  float osc = (z == 0) ? 0.18033688011112042f : 1.0f;  // 0.125 * log2(e)

  int t = threadIdx.x;
  int fid = blockIdx.x;
  int xcd = fid & 7, slot = fid >> 3;
  int m0 = (xcd * 4 + (slot >> 3)) * TM;
  int n0 = (slot & 7) * TN;
  int w = t >> 6, lane = t & 63, c = lane & 15, g = lane >> 4;
  int wr = w >> 1, wc = w & 1;

  f32x4 acc[4][4];
#pragma unroll
  for (int i = 0; i < 4; ++i)
#pragma unroll
    for (int j = 0; j < 4; ++j) acc[i][j] = f32x4{0.f, 0.f, 0.f, 0.f};

  int srcoff = (((t & 7) ^ ((t >> 3) & 7)) << 4);
  int srow = t >> 3;
  const float* aptr[4];
  const __bf16* bptr[4];
#pragma unroll
  for (int i = 0; i < 4; ++i) {
    aptr[i] = A + (size_t)(m0 + i * 32 + srow) * D + (srcoff >> 1);
    bptr[i] = BT + (size_t)(n0 + i * 32 + srow) * D + (srcoff >> 1);
  }

  float4 pa[4][2];
#pragma unroll
  for (int i = 0; i < 4; ++i) {
    pa[i][0] = *(const float4*)(aptr[i]);
    pa[i][1] = *(const float4*)(aptr[i] + 4);
  }
#pragma unroll
  for (int i = 0; i < 4; ++i)
    __builtin_amdgcn_global_load_lds(
        (const __attribute__((address_space(1))) unsigned int*)(bptr[i]),
        (__attribute__((address_space(3))) unsigned int*)((char*)&Bs[0][0] + i * 4096 + t * 16), 16, 0, 0);

  int rswz = ((c & 7) << 4);

  int buf = 0;
  for (int kk = 0; kk < D; kk += BK, buf ^= 1) {
    // 1: issue B(next) into Bs[buf^1]
    if (kk + BK < D) {
#pragma unroll
      for (int i = 0; i < 4; ++i)
        __builtin_amdgcn_global_load_lds(
            (const __attribute__((address_space(1))) unsigned int*)(bptr[i] + kk + BK),
            (__attribute__((address_space(3))) unsigned int*)((char*)&Bs[buf ^ 1][0] + i * 4096 + t * 16), 16, 0, 0);
    }
    // 2: stage A from prefetched regs (implicit wait on pa only)
#pragma unroll
    for (int i = 0; i < 4; ++i) {
      bf16x8 v;
      v[0] = (__bf16)pa[i][0].x; v[1] = (__bf16)pa[i][0].y;
      v[2] = (__bf16)pa[i][0].z; v[3] = (__bf16)pa[i][0].w;
      v[4] = (__bf16)pa[i][1].x; v[5] = (__bf16)pa[i][1].y;
      v[6] = (__bf16)pa[i][1].z; v[7] = (__bf16)pa[i][1].w;
      *(bf16x8*)((char*)As + i * 4096 + t * 16) = v;
    }
    // 3: issue next-A f32 prefetch BEFORE the barrier (latency spans barrier+compute)
    if (kk + BK < D) {
#pragma unroll
      for (int i = 0; i < 4; ++i) {
        pa[i][0] = *(const float4*)(aptr[i] + kk + BK);
        pa[i][1] = *(const float4*)(aptr[i] + kk + BK + 4);
      }
    }
    // 4: counted sync — newer ops in flight: 4 B-next + 8 pa = 12.
    //    vmcnt(12) forces B(cur) (older) complete; lgkm drains A ds_writes.
    if (kk + BK < D)
      asm volatile("s_waitcnt vmcnt(12) lgkmcnt(0)" ::: "memory");
    else
      asm volatile("s_waitcnt vmcnt(0) lgkmcnt(0)" ::: "memory");
    __builtin_amdgcn_s_barrier();
    __builtin_amdgcn_sched_barrier(0);

    // 5: compute from As / Bs[buf]
#pragma unroll
    for (int ks = 0; ks < 2; ++ks) {
      int cb = (ks * 64 + g * 16) ^ rswz;
      bf16x8 af[4], bf[4];
#pragma unroll
      for (int i = 0; i < 4; ++i)
        af[i] = *(const bf16x8*)((char*)As + (wr * 64 + i * 16 + c) * 128 + cb);
#pragma unroll
      for (int j = 0; j < 4; ++j)
        bf[j] = *(const bf16x8*)((char*)&Bs[buf][0] + (wc * 64 + j * 16 + c) * 128 + cb);
#pragma unroll
      for (int i = 0; i < 4; ++i)
#pragma unroll
        for (int j = 0; j < 4; ++j)
          acc[i][j] = __builtin_amdgcn_mfma_f32_16x16x32_bf16(af[i], bf[j], acc[i][j], 0, 0, 0);
    }

    // 6: light end barrier — reads done; vmem stays in flight
    asm volatile("s_waitcnt lgkmcnt(0)" ::: "memory");
    __builtin_amdgcn_s_barrier();
    __builtin_amdgcn_sched_barrier(0);
  }

#pragma unroll
  for (int i = 0; i < 4; ++i)
#pragma unroll
    for (int j = 0; j < 4; ++j) {
      int n = n0 + wc * 64 + j * 16 + c;
      float bv = bias[n];
      int h = n >> 6, dk = n & 63;
#pragma unroll
      for (int q = 0; q < 4; ++q) {
        int mrow = m0 + wr * 64 + i * 16 + g * 4 + q;
        int b = mrow >> 11, s = mrow & (S - 1);
        float val = (acc[i][j][q] + bv) * osc;
        size_t idx;
        if (mode == 0) idx = ((size_t)(b * H + h) * S + s) * DK + dk;
        else           idx = ((size_t)(b * H + h) * DK + dk) * S + s;
        out[idx] = (__bf16)val;
      }
    }
}

// ---------------- flash attention, in-block KV-split (8 waves, 2 halves) ----------------
// Q,K: [BH][S][DK] bf16 (Q pre-scaled by 0.125*log2e); VT: [BH][DK][S] bf16
// out: [B][S][D] f32.  Waves 0-3: kv[0,1024); waves 4-7: kv[1024,2048).
constexpr int HKV = S / 2;           // 1024 kv per half
constexpr int NSTEP = HKV / 64;      // 16 steps of 64 kv per half

__global__ __launch_bounds__(512) void attn(const __bf16* __restrict__ Q,
                                            const __bf16* __restrict__ K,
                                            const __bf16* __restrict__ VT,
                                            float* __restrict__ out) {
  __shared__ __align__(16) char smem[65536];

  int t = threadIdx.x, w = t >> 6, lane = t & 63;
  int half = w >> 2, wl = w & 3;
  int l31 = lane & 31, hi = lane >> 5;
  int th = t & 255;

  int fid = blockIdx.x;
  int xcd = fid & 7, slot = fid >> 3;
  int bh = xcd * 4 + (slot >> 4);
  int q0 = (slot & 15) * 128 + wl * 32;

  const __bf16* Qb = Q + (size_t)bh * S * DK;
  const char* Kg = (const char*)(K + (size_t)bh * S * DK) + (size_t)half * HKV * DK * 2;
  const char* Vg = (const char*)(VT + (size_t)bh * DK * S) + (size_t)half * HKV * 2;

  char* kbase = smem + half * 32768;
  char* vbase = smem + half * 32768 + 16384;

  bf16x8 qf[4];
  {
    const __bf16* qp = Qb + (size_t)(q0 + l31) * DK + hi * 8;
#pragma unroll
    for (int s2 = 0; s2 < 4; ++s2) qf[s2] = *(const bf16x8*)(qp + s2 * 16);
  }

  f32x16 ZERO;
#pragma unroll
  for (int r = 0; r < 16; ++r) ZERO[r] = 0.f;

  f32x16 acc0, acc1;
#pragma unroll
  for (int r = 0; r < 16; ++r) { acc0[r] = 0.f; acc1[r] = 0.f; }
  float lrun = 0.f;

  int krow = ((l31 >> 2) & 1) * 8 + ((l31 >> 3) & 1) * 16 + ((l31 >> 4) & 1) * 4 + (l31 & 3);
  int kswz = (((krow & 7) ^ ((krow >> 3) & 3)) << 4);
  int vswz = (((l31 & 7) ^ ((l31 >> 3) & 3)) << 4);

  auto stage = [&](int bufi, int kstep) {
#pragma unroll
    for (int i = 0; i < 2; ++i) {
      int L = i * 4096 + th * 16;
      int row = L >> 7;
      int sz = (((row & 7) ^ ((row >> 3) & 3)) << 4);
      __builtin_amdgcn_global_load_lds(
          (const __attribute__((address_space(1))) unsigned int*)(Kg + (size_t)kstep * 8192 + (L ^ sz)),
          (__attribute__((address_space(3))) unsigned int*)(kbase + bufi * 8192 + L), 16, 0, 0);
      __builtin_amdgcn_global_load_lds(
          (const __attribute__((address_space(1))) unsigned int*)(Vg + (size_t)row * (S * 2) + kstep * 128 + ((L & 127) ^ sz)),
          (__attribute__((address_space(3))) unsigned int*)(vbase + bufi * 8192 + L), 16, 0, 0);
    }
  };

  auto loadFrag = [&](const char* kb, const char* vb, int sub, bf16x8* Kf, bf16x8* Vf) {
    const char* kr = kb + ((sub * 32 + krow) << 7);
#pragma unroll
    for (int s2 = 0; s2 < 4; ++s2)
      Kf[s2] = *(const bf16x8*)(kr + ((s2 * 32 + hi * 16) ^ kswz));
#pragma unroll
    for (int ks = 0; ks < 2; ++ks)
#pragma unroll
      for (int db = 0; db < 2; ++db)
        Vf[ks * 2 + db] = *(const bf16x8*)(vb + ((db * 32 + l31) << 7) +
                                           ((sub * 64 + ks * 32 + hi * 16) ^ vswz));
  };

  auto computeQK = [&](bf16x8* Kf) -> f32x16 {
    __builtin_amdgcn_s_setprio(1);
    f32x16 st = __builtin_amdgcn_mfma_f32_32x32x16_bf16(Kf[0], qf[0], ZERO, 0, 0, 0);
    st = __builtin_amdgcn_mfma_f32_32x32x16_bf16(Kf[1], qf[1], st, 0, 0, 0);
    st = __builtin_amdgcn_mfma_f32_32x32x16_bf16(Kf[2], qf[2], st, 0, 0, 0);
    st = __builtin_amdgcn_mfma_f32_32x32x16_bf16(Kf[3], qf[3], st, 0, 0, 0);
    __builtin_amdgcn_s_setprio(0);
    return st;
  };

  auto computeSMPV = [&](const f32x16& st, bf16x8* Vf) {
    float p[16];
#pragma unroll
    for (int r = 0; r < 16; ++r) p[r] = fexp2(st[r]);
    {
      float t0 = (p[0] + p[1]) + (p[2] + p[3]);
      float t1 = (p[4] + p[5]) + (p[6] + p[7]);
      float t2 = (p[8] + p[9]) + (p[10] + p[11]);
      float t3 = (p[12] + p[13]) + (p[14] + p[15]);
      lrun += (t0 + t1) + (t2 + t3);
    }
    union Pk { unsigned u[4]; bf16x8 v; } P0, P1;
    P0.u[0] = pk2(p[0], p[1]);   P0.u[1] = pk2(p[2], p[3]);
    P0.u[2] = pk2(p[8], p[9]);   P0.u[3] = pk2(p[10], p[11]);
    P1.u[0] = pk2(p[4], p[5]);   P1.u[1] = pk2(p[6], p[7]);
    P1.u[2] = pk2(p[12], p[13]); P1.u[3] = pk2(p[14], p[15]);

    __builtin_amdgcn_s_setprio(1);
    acc0 = __builtin_amdgcn_mfma_f32_32x32x16_bf16(P0.v, Vf[0], acc0, 0, 0, 0);
    acc1 = __builtin_amdgcn_mfma_f32_32x32x16_bf16(P0.v, Vf[1], acc1, 0, 0, 0);
    acc0 = __builtin_amdgcn_mfma_f32_32x32x16_bf16(P1.v, Vf[2], acc0, 0, 0, 0);
    acc1 = __builtin_amdgcn_mfma_f32_32x32x16_bf16(P1.v, Vf[3], acc1, 0, 0, 0);
    __builtin_amdgcn_s_setprio(0);
  };

  stage(0, 0);
  __syncthreads();

  bf16x8 KfA[4], VfA[4], KfB[4], VfB[4];
  for (int tt = 0; tt < NSTEP; ++tt) {
    int cur = tt & 1;
    const char* kb = kbase + cur * 8192;
    const char* vb = vbase + cur * 8192;

    // ds_reads (critical path to QK) issue before the stage's vmem ops
    loadFrag(kb, vb, 0, KfA, VfA);
    loadFrag(kb, vb, 1, KfB, VfB);
    if (tt + 1 < NSTEP) stage(cur ^ 1, tt + 1);

    f32x16 stA = computeQK(KfA);
    f32x16 stB = computeQK(KfB);
    computeSMPV(stA, VfA);        // overlaps stB's MFMA chain
    computeSMPV(stB, VfB);

    __syncthreads();
  }

  // ---- combine the two halves in LDS (addition-only, static-max softmax) ----
  lrun += __shfl_xor(lrun, 32);
  __syncthreads();

  float* xch = (float*)smem;
  int xi = (wl * 64 + lane) * 33;
  if (half == 1) {
#pragma unroll
    for (int r = 0; r < 16; ++r) {
      xch[xi + r] = acc0[r];
      xch[xi + 16 + r] = acc1[r];
    }
    xch[xi + 32] = lrun;
  }
  __syncthreads();

  if (half == 0) {
    float lt = lrun + xch[xi + 32];
    int b = bh >> 4, h = bh & 15;
#pragma unroll
    for (int r = 0; r < 16; ++r) {
      int rowq = (r & 3) + 8 * (r >> 2) + 4 * hi;
      float li = __shfl(lt, rowq);
      float ri = frcp(li);
      size_t base = (size_t)(b * S + q0 + rowq) * D + h * 64 + l31;
      out[base] = (acc0[r] + xch[xi + r]) * ri;
      out[base + 32] = (acc1[r] + xch[xi + 16 + r]) * ri;
    }
  }
}

extern "C" void kernel_launch(void* const* d_in, const int* in_sizes, int n_in,
                              void* d_out, int out_size, void* d_ws, size_t ws_size,
                              hipStream_t stream) {
  (void)in_sizes; (void)n_in; (void)out_size; (void)ws_size;
  const float* xq = (const float*)d_in[0];
  const float* xk = (const float*)d_in[1];
  const float* xv = (const float*)d_in[2];
  const float* Wq = (const float*)d_in[3];
  const float* bq = (const float*)d_in[4];
  const float* Wk = (const float*)d_in[5];
  const float* bk = (const float*)d_in[6];
  const float* Wv = (const float*)d_in[7];
  const float* bv = (const float*)d_in[8];

  char* ws = (char*)d_ws;
  const size_t MB = 1u << 20;
  __bf16* WT[3] = {(__bf16*)(ws + 24 * MB), (__bf16*)(ws + 26 * MB), (__bf16*)(ws + 28 * MB)};
  __bf16* Qb = (__bf16*)(ws + 30 * MB);
  __bf16* Kb = (__bf16*)(ws + 38 * MB);
  __bf16* Vt = (__bf16*)(ws + 46 * MB);

  wtrans3<<<dim3(D / 32, D / 32, 3), 256, 0, stream>>>(Wq, Wk, Wv, WT[0], WT[1], WT[2]);
  proj3<<<dim3(256, 1, 3), 256, 0, stream>>>(xq, xk, xv,
                                             WT[0], WT[1], WT[2],
                                             bq, bk, bv, Qb, Kb, Vt);
  attn<<<dim3(512), 512, 0, stream>>>(Qb, Kb, Vt, (float*)d_out);
}

// Round 21
// 93.334 us; speedup vs baseline: 1.0119x; 1.0119x over previous
//
#include <hip/hip_runtime.h>
#include <hip/hip_bf16.h>

typedef __bf16 bf16x4 __attribute__((ext_vector_type(4)));
typedef __bf16 bf16x8 __attribute__((ext_vector_type(8)));
typedef float  f32x4  __attribute__((ext_vector_type(4)));
typedef float  f32x16 __attribute__((ext_vector_type(16)));

constexpr int B = 2, S = 2048, D = 1024, H = 16, DK = 64;
constexpr int M = B * S;
constexpr int BH = B * H;

__device__ inline float fexp2(float x) {
#if __has_builtin(__builtin_amdgcn_exp2f)
  return __builtin_amdgcn_exp2f(x);
#else
  return exp2f(x);
#endif
}
__device__ inline float frcp(float x) {
#if __has_builtin(__builtin_amdgcn_rcpf)
  return __builtin_amdgcn_rcpf(x);
#else
  return 1.0f / x;
#endif
}
__device__ inline unsigned pk2(float lo, float hi) {
  union { __bf16 h[2]; unsigned u; } x;
  x.h[0] = (__bf16)lo; x.h[1] = (__bf16)hi;
  return x.u;
}

// ---------------- W [K][N] f32 -> WT [N][K] bf16, 3 in one launch ----------------
__global__ __launch_bounds__(256) void wtrans3(const float* __restrict__ w0,
                                               const float* __restrict__ w1,
                                               const float* __restrict__ w2,
                                               __bf16* __restrict__ t0,
                                               __bf16* __restrict__ t1,
                                               __bf16* __restrict__ t2) {
  int z = blockIdx.z;
  const float* W = z == 0 ? w0 : z == 1 ? w1 : w2;
  __bf16* WT = z == 0 ? t0 : z == 1 ? t1 : t2;
  __shared__ float t[32][33];
  int tx = threadIdx.x & 31, ty0 = threadIdx.x >> 5;
  int n0 = blockIdx.x * 32, k0 = blockIdx.y * 32;
#pragma unroll
  for (int i = 0; i < 4; ++i)
    t[ty0 + i * 8][tx] = W[(size_t)(k0 + ty0 + i * 8) * D + n0 + tx];
  __syncthreads();
#pragma unroll
  for (int i = 0; i < 4; ++i)
    WT[(size_t)(n0 + ty0 + i * 8) * D + k0 + tx] = (__bf16)t[tx][ty0 + i * 8];
}

// ---------------- merged projection GEMMs, f32-A fused conversion, BK=64 ----------------
constexpr int TM = 128, TN = 128, BK = 64;

__global__ __launch_bounds__(256, 3) void proj3(
    const float* __restrict__ X0, const float* __restrict__ X1,
    const float* __restrict__ X2, const __bf16* __restrict__ W0,
    const __bf16* __restrict__ W1, const __bf16* __restrict__ W2,
    const float* __restrict__ b0, const float* __restrict__ b1,
    const float* __restrict__ b2, __bf16* __restrict__ Qo,
    __bf16* __restrict__ Ko, __bf16* __restrict__ Vo) {
  __shared__ __align__(16) __bf16 As[TM * BK];      // 16 KB, single
  __shared__ __align__(16) __bf16 Bs[2][TN * BK];   // 2 x 16 KB
  int z = blockIdx.z;
  const float* A   = z == 0 ? X0 : z == 1 ? X1 : X2;
  const __bf16* BT = z == 0 ? W0 : z == 1 ? W1 : W2;
  const float* bias = z == 0 ? b0 : z == 1 ? b1 : b2;
  __bf16* out = z == 0 ? Qo : z == 1 ? Ko : Vo;
  int mode = (z == 2) ? 1 : 0;
  float osc = (z == 0) ? 0.18033688011112042f : 1.0f;  // 0.125 * log2(e)

  int t = threadIdx.x;
  int fid = blockIdx.x;
  int xcd = fid & 7, slot = fid >> 3;
  int m0 = (xcd * 4 + (slot >> 3)) * TM;
  int n0 = (slot & 7) * TN;
  int w = t >> 6, lane = t & 63, c = lane & 15, g = lane >> 4;
  int wr = w >> 1, wc = w & 1;

  f32x4 acc[4][4];
#pragma unroll
  for (int i = 0; i < 4; ++i)
#pragma unroll
    for (int j = 0; j < 4; ++j) acc[i][j] = f32x4{0.f, 0.f, 0.f, 0.f};

  int srcoff = (((t & 7) ^ ((t >> 3) & 7)) << 4);
  int srow = t >> 3;
  const float* aptr[4];
  const __bf16* bptr[4];
#pragma unroll
  for (int i = 0; i < 4; ++i) {
    aptr[i] = A + (size_t)(m0 + i * 32 + srow) * D + (srcoff >> 1);
    bptr[i] = BT + (size_t)(n0 + i * 32 + srow) * D + (srcoff >> 1);
  }

  float4 pa[4][2];
#pragma unroll
  for (int i = 0; i < 4; ++i) {
    pa[i][0] = *(const float4*)(aptr[i]);
    pa[i][1] = *(const float4*)(aptr[i] + 4);
  }
#pragma unroll
  for (int i = 0; i < 4; ++i)
    __builtin_amdgcn_global_load_lds(
        (const __attribute__((address_space(1))) unsigned int*)(bptr[i]),
        (__attribute__((address_space(3))) unsigned int*)((char*)&Bs[0][0] + i * 4096 + t * 16), 16, 0, 0);

  int rswz = ((c & 7) << 4);

  int buf = 0;
  for (int kk = 0; kk < D; kk += BK, buf ^= 1) {
    // 1: issue B(next) into Bs[buf^1] (newest 4 vmem ops; span the barrier)
    if (kk + BK < D) {
#pragma unroll
      for (int i = 0; i < 4; ++i)
        __builtin_amdgcn_global_load_lds(
            (const __attribute__((address_space(1))) unsigned int*)(bptr[i] + kk + BK),
            (__attribute__((address_space(3))) unsigned int*)((char*)&Bs[buf ^ 1][0] + i * 4096 + t * 16), 16, 0, 0);
    }
    // 2: stage A (convert f32->bf16; implicit pa-wait leaves newest 4 B loads in flight)
#pragma unroll
    for (int i = 0; i < 4; ++i) {
      bf16x8 v;
      v[0] = (__bf16)pa[i][0].x; v[1] = (__bf16)pa[i][0].y;
      v[2] = (__bf16)pa[i][0].z; v[3] = (__bf16)pa[i][0].w;
      v[4] = (__bf16)pa[i][1].x; v[5] = (__bf16)pa[i][1].y;
      v[6] = (__bf16)pa[i][1].z; v[7] = (__bf16)pa[i][1].w;
      *(bf16x8*)((char*)As + i * 4096 + t * 16) = v;
    }
    // 3: counted sync — B(cur) landed, A-writes visible, B(next) still in flight
    if (kk + BK < D)
      asm volatile("s_waitcnt vmcnt(4) lgkmcnt(0)" ::: "memory");
    else
      asm volatile("s_waitcnt vmcnt(0) lgkmcnt(0)" ::: "memory");
    __builtin_amdgcn_s_barrier();
    __builtin_amdgcn_sched_barrier(0);

    // 4: prefetch next A slab (hidden under MFMAs)
    if (kk + BK < D) {
#pragma unroll
      for (int i = 0; i < 4; ++i) {
        pa[i][0] = *(const float4*)(aptr[i] + kk + BK);
        pa[i][1] = *(const float4*)(aptr[i] + kk + BK + 4);
      }
    }

    // 5: compute from As / Bs[buf]
#pragma unroll
    for (int ks = 0; ks < 2; ++ks) {
      int cb = (ks * 64 + g * 16) ^ rswz;
      bf16x8 af[4], bf[4];
#pragma unroll
      for (int i = 0; i < 4; ++i)
        af[i] = *(const bf16x8*)((char*)As + (wr * 64 + i * 16 + c) * 128 + cb);
#pragma unroll
      for (int j = 0; j < 4; ++j)
        bf[j] = *(const bf16x8*)((char*)&Bs[buf][0] + (wc * 64 + j * 16 + c) * 128 + cb);
#pragma unroll
      for (int i = 0; i < 4; ++i)
#pragma unroll
        for (int j = 0; j < 4; ++j)
          acc[i][j] = __builtin_amdgcn_mfma_f32_16x16x32_bf16(af[i], bf[j], acc[i][j], 0, 0, 0);
    }

    // 6: light end barrier — reads done; vmem (B-next, pa) stays in flight
    asm volatile("s_waitcnt lgkmcnt(0)" ::: "memory");
    __builtin_amdgcn_s_barrier();
    __builtin_amdgcn_sched_barrier(0);
  }

#pragma unroll
  for (int i = 0; i < 4; ++i)
#pragma unroll
    for (int j = 0; j < 4; ++j) {
      int n = n0 + wc * 64 + j * 16 + c;
      float bv = bias[n];
      int h = n >> 6, dk = n & 63;
#pragma unroll
      for (int q = 0; q < 4; ++q) {
        int mrow = m0 + wr * 64 + i * 16 + g * 4 + q;
        int b = mrow >> 11, s = mrow & (S - 1);
        float val = (acc[i][j][q] + bv) * osc;
        size_t idx;
        if (mode == 0) idx = ((size_t)(b * H + h) * S + s) * DK + dk;
        else           idx = ((size_t)(b * H + h) * DK + dk) * S + s;
        out[idx] = (__bf16)val;
      }
    }
}

// ---------------- flash attention, in-block KV-split (8 waves, 2 halves) ----------------
// Q,K: [BH][S][DK] bf16 (Q pre-scaled by 0.125*log2e); VT: [BH][DK][S] bf16
// out: [B][S][D] f32.  Waves 0-3: kv[0,1024); waves 4-7: kv[1024,2048).
// Static-max softmax => partials combine by pure addition in LDS.
constexpr int HKV = S / 2;           // 1024 kv per half
constexpr int NSTEP = HKV / 64;      // 16 steps of 64 kv per half

__global__ __launch_bounds__(512) void attn(const __bf16* __restrict__ Q,
                                            const __bf16* __restrict__ K,
                                            const __bf16* __restrict__ VT,
                                            float* __restrict__ out) {
  __shared__ __align__(16) char smem[65536];

  int t = threadIdx.x, w = t >> 6, lane = t & 63;
  int half = w >> 2, wl = w & 3;
  int l31 = lane & 31, hi = lane >> 5;
  int th = t & 255;

  int fid = blockIdx.x;
  int xcd = fid & 7, slot = fid >> 3;
  int bh = xcd * 4 + (slot >> 4);
  int q0 = (slot & 15) * 128 + wl * 32;

  const __bf16* Qb = Q + (size_t)bh * S * DK;
  const char* Kg = (const char*)(K + (size_t)bh * S * DK) + (size_t)half * HKV * DK * 2;
  const char* Vg = (const char*)(VT + (size_t)bh * DK * S) + (size_t)half * HKV * 2;

  char* kbase = smem + half * 32768;
  char* vbase = smem + half * 32768 + 16384;

  bf16x8 qf[4];
  {
    const __bf16* qp = Qb + (size_t)(q0 + l31) * DK + hi * 8;
#pragma unroll
    for (int s2 = 0; s2 < 4; ++s2) qf[s2] = *(const bf16x8*)(qp + s2 * 16);
  }

  f32x16 ZERO;
#pragma unroll
  for (int r = 0; r < 16; ++r) ZERO[r] = 0.f;

  f32x16 acc0, acc1;
#pragma unroll
  for (int r = 0; r < 16; ++r) { acc0[r] = 0.f; acc1[r] = 0.f; }
  float lrun = 0.f;

  // zero-shuffle P->A: read K row pi(l31); pi(a+4h+8b) = h*8 + (b&1)*16 + (b>>1)*4 + a
  int krow = ((l31 >> 2) & 1) * 8 + ((l31 >> 3) & 1) * 16 + ((l31 >> 4) & 1) * 4 + (l31 & 3);
  int kswz = (((krow & 7) ^ ((krow >> 3) & 3)) << 4);
  int vswz = (((l31 & 7) ^ ((l31 >> 3) & 3)) << 4);

  auto stage = [&](int bufi, int kstep) {
#pragma unroll
    for (int i = 0; i < 2; ++i) {
      int L = i * 4096 + th * 16;
      int row = L >> 7;
      int sz = (((row & 7) ^ ((row >> 3) & 3)) << 4);
      __builtin_amdgcn_global_load_lds(
          (const __attribute__((address_space(1))) unsigned int*)(Kg + (size_t)kstep * 8192 + (L ^ sz)),
          (__attribute__((address_space(3))) unsigned int*)(kbase + bufi * 8192 + L), 16, 0, 0);
      __builtin_amdgcn_global_load_lds(
          (const __attribute__((address_space(1))) unsigned int*)(Vg + (size_t)row * (S * 2) + kstep * 128 + ((L & 127) ^ sz)),
          (__attribute__((address_space(3))) unsigned int*)(vbase + bufi * 8192 + L), 16, 0, 0);
    }
  };

  auto loadFrag = [&](const char* kb, const char* vb, int sub, bf16x8* Kf, bf16x8* Vf) {
    const char* kr = kb + ((sub * 32 + krow) << 7);
#pragma unroll
    for (int s2 = 0; s2 < 4; ++s2)
      Kf[s2] = *(const bf16x8*)(kr + ((s2 * 32 + hi * 16) ^ kswz));
#pragma unroll
    for (int ks = 0; ks < 2; ++ks)
#pragma unroll
      for (int db = 0; db < 2; ++db)
        Vf[ks * 2 + db] = *(const bf16x8*)(vb + ((db * 32 + l31) << 7) +
                                           ((sub * 64 + ks * 32 + hi * 16) ^ vswz));
  };

  auto computeQK = [&](bf16x8* Kf) -> f32x16 {
    __builtin_amdgcn_s_setprio(1);
    f32x16 st = __builtin_amdgcn_mfma_f32_32x32x16_bf16(Kf[0], qf[0], ZERO, 0, 0, 0);
    st = __builtin_amdgcn_mfma_f32_32x32x16_bf16(Kf[1], qf[1], st, 0, 0, 0);
    st = __builtin_amdgcn_mfma_f32_32x32x16_bf16(Kf[2], qf[2], st, 0, 0, 0);
    st = __builtin_amdgcn_mfma_f32_32x32x16_bf16(Kf[3], qf[3], st, 0, 0, 0);
    __builtin_amdgcn_s_setprio(0);
    return st;
  };

  auto computeSMPV = [&](const f32x16& st, bf16x8* Vf) {
    float p[16];
#pragma unroll
    for (int r = 0; r < 16; ++r) p[r] = fexp2(st[r]);
    {
      float t0 = (p[0] + p[1]) + (p[2] + p[3]);
      float t1 = (p[4] + p[5]) + (p[6] + p[7]);
      float t2 = (p[8] + p[9]) + (p[10] + p[11]);
      float t3 = (p[12] + p[13]) + (p[14] + p[15]);
      lrun += (t0 + t1) + (t2 + t3);
    }
    union Pk { unsigned u[4]; bf16x8 v; } P0, P1;
    P0.u[0] = pk2(p[0], p[1]);   P0.u[1] = pk2(p[2], p[3]);
    P0.u[2] = pk2(p[8], p[9]);   P0.u[3] = pk2(p[10], p[11]);
    P1.u[0] = pk2(p[4], p[5]);   P1.u[1] = pk2(p[6], p[7]);
    P1.u[2] = pk2(p[12], p[13]); P1.u[3] = pk2(p[14], p[15]);

    __builtin_amdgcn_s_setprio(1);
    acc0 = __builtin_amdgcn_mfma_f32_32x32x16_bf16(P0.v, Vf[0], acc0, 0, 0, 0);
    acc1 = __builtin_amdgcn_mfma_f32_32x32x16_bf16(P0.v, Vf[1], acc1, 0, 0, 0);
    acc0 = __builtin_amdgcn_mfma_f32_32x32x16_bf16(P1.v, Vf[2], acc0, 0, 0, 0);
    acc1 = __builtin_amdgcn_mfma_f32_32x32x16_bf16(P1.v, Vf[3], acc1, 0, 0, 0);
    __builtin_amdgcn_s_setprio(0);
  };

  stage(0, 0);
  __syncthreads();

  bf16x8 KfA[4], VfA[4], KfB[4], VfB[4];
  for (int tt = 0; tt < NSTEP; ++tt) {
    int cur = tt & 1;
    if (tt + 1 < NSTEP) stage(cur ^ 1, tt + 1);
    const char* kb = kbase + cur * 8192;
    const char* vb = vbase + cur * 8192;

    // 2-chain pipeline across the two 32-kv subs of this 64-kv step
    loadFrag(kb, vb, 0, KfA, VfA);
    loadFrag(kb, vb, 1, KfB, VfB);
    f32x16 stA = computeQK(KfA);
    f32x16 stB = computeQK(KfB);
    computeSMPV(stA, VfA);        // overlaps stB's MFMA chain
    computeSMPV(stB, VfB);

    __syncthreads();
  }

  // ---- combine the two halves in LDS (addition-only, static-max softmax) ----
  lrun += __shfl_xor(lrun, 32);
  __syncthreads();

  float* xch = (float*)smem;
  int xi = (wl * 64 + lane) * 33;
  if (half == 1) {
#pragma unroll
    for (int r = 0; r < 16; ++r) {
      xch[xi + r] = acc0[r];
      xch[xi + 16 + r] = acc1[r];
    }
    xch[xi + 32] = lrun;
  }
  __syncthreads();

  if (half == 0) {
    float lt = lrun + xch[xi + 32];
    int b = bh >> 4, h = bh & 15;
#pragma unroll
    for (int r = 0; r < 16; ++r) {
      int rowq = (r & 3) + 8 * (r >> 2) + 4 * hi;
      float li = __shfl(lt, rowq);
      float ri = frcp(li);
      size_t base = (size_t)(b * S + q0 + rowq) * D + h * 64 + l31;
      out[base] = (acc0[r] + xch[xi + r]) * ri;
      out[base + 32] = (acc1[r] + xch[xi + 16 + r]) * ri;
    }
  }
}

extern "C" void kernel_launch(void* const* d_in, const int* in_sizes, int n_in,
                              void* d_out, int out_size, void* d_ws, size_t ws_size,
                              hipStream_t stream) {
  (void)in_sizes; (void)n_in; (void)out_size; (void)ws_size;
  const float* xq = (const float*)d_in[0];
  const float* xk = (const float*)d_in[1];
  const float* xv = (const float*)d_in[2];
  const float* Wq = (const float*)d_in[3];
  const float* bq = (const float*)d_in[4];
  const float* Wk = (const float*)d_in[5];
  const float* bk = (const float*)d_in[6];
  const float* Wv = (const float*)d_in[7];
  const float* bv = (const float*)d_in[8];

  char* ws = (char*)d_ws;
  const size_t MB = 1u << 20;
  __bf16* WT[3] = {(__bf16*)(ws + 24 * MB), (__bf16*)(ws + 26 * MB), (__bf16*)(ws + 28 * MB)};
  __bf16* Qb = (__bf16*)(ws + 30 * MB);
  __bf16* Kb = (__bf16*)(ws + 38 * MB);
  __bf16* Vt = (__bf16*)(ws + 46 * MB);

  wtrans3<<<dim3(D / 32, D / 32, 3), 256, 0, stream>>>(Wq, Wk, Wv, WT[0], WT[1], WT[2]);
  proj3<<<dim3(256, 1, 3), 256, 0, stream>>>(xq, xk, xv,
                                             WT[0], WT[1], WT[2],
                                             bq, bk, bv, Qb, Kb, Vt);
  attn<<<dim3(512), 512, 0, stream>>>(Qb, Kb, Vt, (float*)d_out);
}